// Round 1
// baseline (950.569 us; speedup 1.0000x reference)
//
#include <hip/hip_runtime.h>
#include <hip/hip_bf16.h>

typedef __bf16 bf16;
typedef __attribute__((ext_vector_type(8))) __bf16 bf16x8;
typedef __attribute__((ext_vector_type(4))) float f32x4;

#define LAMBDA_INIT_F 0.3555090675909693f
#define RMS_EPS 1e-5f

// ---------------------------------------------------------------- cast f32 -> bf16
__global__ void cast_f32_bf16(const float* __restrict__ in, bf16* __restrict__ out, int n4) {
  int idx = blockIdx.x * blockDim.x + threadIdx.x;
  int stride = gridDim.x * blockDim.x;
  for (int i = idx; i < n4; i += stride) {
    float4 v = reinterpret_cast<const float4*>(in)[i];
    bf16 o[4];
    o[0] = (bf16)v.x; o[1] = (bf16)v.y; o[2] = (bf16)v.z; o[3] = (bf16)v.w;
    *reinterpret_cast<ushort4*>(&out[(size_t)i * 4]) = *reinterpret_cast<const ushort4*>(o);
  }
}

// ---------------------------------------------------------------- bt-GEMM
// C[m,n] = sum_k A[m,k] * B[n,k]   (A: MxK row-major, B: NxK row-major)
template <typename OUT_T>
__global__ __launch_bounds__(256) void gemm_bt(
    const bf16* __restrict__ A, const bf16* __restrict__ B,
    OUT_T* __restrict__ C, int M, int N, int K) {
  constexpr int BM = 128, BN = 128, BK = 32, LDP = BK + 8;  // pad keeps 16B align (80B rows)
  __shared__ __align__(16) bf16 As[BM][LDP];
  __shared__ __align__(16) bf16 Bs[BN][LDP];
  const int tid = threadIdx.x;
  const int lane = tid & 63;
  const int w = tid >> 6;
  const int wr = (w >> 1) * 64, wc = (w & 1) * 64;
  const int l15 = lane & 15, lhi = lane >> 4;
  const int bm = blockIdx.x * BM, bn = blockIdx.y * BN;
  f32x4 acc[4][4] = {};

  for (int k0 = 0; k0 < K; k0 += BK) {
    __syncthreads();
#pragma unroll
    for (int i = 0; i < 2; ++i) {
      int f = i * 256 + tid;   // 0..511 ; 4 threads per 32-elem row
      int row = f >> 2;
      int c8 = (f & 3) * 8;
      *reinterpret_cast<uint4*>(&As[row][c8]) =
          *reinterpret_cast<const uint4*>(&A[(size_t)(bm + row) * K + k0 + c8]);
      *reinterpret_cast<uint4*>(&Bs[row][c8]) =
          *reinterpret_cast<const uint4*>(&B[(size_t)(bn + row) * K + k0 + c8]);
    }
    __syncthreads();
    bf16x8 af[4], bfr[4];
#pragma unroll
    for (int mf = 0; mf < 4; ++mf)
      af[mf] = *reinterpret_cast<const bf16x8*>(&As[wr + mf * 16 + l15][lhi * 8]);
#pragma unroll
    for (int nf = 0; nf < 4; ++nf)
      bfr[nf] = *reinterpret_cast<const bf16x8*>(&Bs[wc + nf * 16 + l15][lhi * 8]);
#pragma unroll
    for (int mf = 0; mf < 4; ++mf)
#pragma unroll
      for (int nf = 0; nf < 4; ++nf)
        acc[mf][nf] = __builtin_amdgcn_mfma_f32_16x16x32_bf16(af[mf], bfr[nf], acc[mf][nf], 0, 0, 0);
  }
  // epilogue: C/D layout col=lane&15, row=(lane>>4)*4+r
#pragma unroll
  for (int mf = 0; mf < 4; ++mf)
#pragma unroll
    for (int nf = 0; nf < 4; ++nf)
#pragma unroll
      for (int r = 0; r < 4; ++r) {
        int m = bm + wr + mf * 16 + lhi * 4 + r;
        int n = bn + wc + nf * 16 + l15;
        C[(size_t)m * N + n] = (OUT_T)acc[mf][nf][r];
      }
}

// ---------------------------------------------------------------- differential flash attention
// grid: (N/64, H, B), block 256 (4 waves x 16 q-rows)
__global__ __launch_bounds__(256) void diff_attn(
    const bf16* __restrict__ Q, const bf16* __restrict__ Kb, const bf16* __restrict__ Vb,
    const float* __restrict__ lq1, const float* __restrict__ lk1,
    const float* __restrict__ lq2, const float* __restrict__ lk2,
    const float* __restrict__ rms_scale, bf16* __restrict__ Ob) {
  constexpr int NSEQ = 2048, E = 2048, KT = 32;
  __shared__ __align__(16) bf16 Ks[KT][264];       // key-major, 256 dims + pad8 (row 528B = 33*16)
  __shared__ __align__(16) bf16 Vt[256][KT + 8];   // e-major (transposed), row 80B
  __shared__ __align__(16) bf16 Ps[4][16][KT + 8]; // per-wave P staging
  const int tid = threadIdx.x, lane = tid & 63, w = tid >> 6;
  const int l15 = lane & 15, lhi = lane >> 4;
  const int b = blockIdx.z, h = blockIdx.y;
  const int q0 = blockIdx.x * 64;

  // lambda scalar for this head (redundant per-thread, tiny & cached)
  float sl1 = 0.f, sl2 = 0.f;
  for (int i = 0; i < 128; ++i) {
    sl1 += lq1[h * 128 + i] * lk1[h * 128 + i];
    sl2 += lq2[h * 128 + i] * lk2[h * 128 + i];
  }
  const float lam = __expf(sl1) - __expf(sl2) + LAMBDA_INIT_F;

  // Q fragments for this wave's 16 rows (A-frag: row = lane&15, k = lhi*8+j)
  const int qrow = q0 + w * 16 + l15;
  const size_t qbase = ((size_t)b * NSEQ + qrow) * E + (size_t)h * 256;
  bf16x8 q1f[4], q2f[4];
#pragma unroll
  for (int df = 0; df < 4; ++df) {
    q1f[df] = *reinterpret_cast<const bf16x8*>(&Q[qbase + df * 32 + lhi * 8]);
    q2f[df] = *reinterpret_cast<const bf16x8*>(&Q[qbase + 128 + df * 32 + lhi * 8]);
  }

  f32x4 o1[16] = {}, o2[16] = {};
  float m1[4], l1[4], m2[4], l2[4];
#pragma unroll
  for (int r = 0; r < 4; ++r) { m1[r] = m2[r] = -1e30f; l1[r] = l2[r] = 0.f; }

  auto stream_step = [&](int d0, const bf16x8* qf, float* mm, float* ll, f32x4* oo) {
    f32x4 s[2] = {};
#pragma unroll
    for (int cb = 0; cb < 2; ++cb)
#pragma unroll
      for (int df = 0; df < 4; ++df) {
        bf16x8 kf = *reinterpret_cast<const bf16x8*>(&Ks[cb * 16 + l15][d0 + df * 32 + lhi * 8]);
        s[cb] = __builtin_amdgcn_mfma_f32_16x16x32_bf16(qf[df], kf, s[cb], 0, 0, 0);
      }
    constexpr float sc = 0.08838834764831845f;  // 1/sqrt(128)
    float alpha[4];
#pragma unroll
    for (int r = 0; r < 4; ++r) {
      float v0 = s[0][r] * sc, v1 = s[1][r] * sc;
      float mx = fmaxf(v0, v1);
#pragma unroll
      for (int off = 1; off < 16; off <<= 1) mx = fmaxf(mx, __shfl_xor(mx, off, 64));
      float mnew = fmaxf(mm[r], mx);
      float al = __expf(mm[r] - mnew);
      float p0 = __expf(v0 - mnew);
      float p1 = __expf(v1 - mnew);
      float rsum = p0 + p1;
#pragma unroll
      for (int off = 1; off < 16; off <<= 1) rsum += __shfl_xor(rsum, off, 64);
      ll[r] = ll[r] * al + rsum;
      mm[r] = mnew;
      alpha[r] = al;
      s[0][r] = p0; s[1][r] = p1;
    }
#pragma unroll
    for (int eb = 0; eb < 16; ++eb) {
      oo[eb][0] *= alpha[0]; oo[eb][1] *= alpha[1];
      oo[eb][2] *= alpha[2]; oo[eb][3] *= alpha[3];
    }
    // P -> LDS (S layout: col=lane&15 is key, row=lhi*4+r is q)
#pragma unroll
    for (int cb = 0; cb < 2; ++cb)
#pragma unroll
      for (int r = 0; r < 4; ++r)
        Ps[w][lhi * 4 + r][cb * 16 + l15] = (bf16)s[cb][r];
    __syncthreads();  // ordering insurance (uniform for all waves)
    bf16x8 pa = *reinterpret_cast<const bf16x8*>(&Ps[w][l15][lhi * 8]);
#pragma unroll
    for (int eb = 0; eb < 16; ++eb) {
      bf16x8 vf = *reinterpret_cast<const bf16x8*>(&Vt[eb * 16 + l15][lhi * 8]);
      oo[eb] = __builtin_amdgcn_mfma_f32_16x16x32_bf16(pa, vf, oo[eb], 0, 0, 0);
    }
  };

  for (int kt0 = 0; kt0 < NSEQ; kt0 += KT) {
    __syncthreads();
    // stage K tile (row-major) and V tile (transposed to e-major)
#pragma unroll
    for (int i = 0; i < 4; ++i) {
      int f = i * 256 + tid;       // 0..1023 ; 32 loaders per key-row
      int key = f >> 5;
      int e8 = (f & 31) * 8;
      const size_t gb = ((size_t)b * NSEQ + kt0 + key) * E + (size_t)h * 256 + e8;
      *reinterpret_cast<uint4*>(&Ks[key][e8]) = *reinterpret_cast<const uint4*>(&Kb[gb]);
      uint4 vv = *reinterpret_cast<const uint4*>(&Vb[gb]);
      bf16 tmp[8];
      *reinterpret_cast<uint4*>(tmp) = vv;
#pragma unroll
      for (int j = 0; j < 8; ++j) Vt[e8 + j][key] = tmp[j];
    }
    __syncthreads();
    stream_step(0,   q1f, m1, l1, o1);
    stream_step(128, q2f, m2, l2, o2);
  }

  // epilogue: combine streams, RMS norm over 256 dims, scale, store bf16
  const float osc = 1.0f - LAMBDA_INIT_F;
#pragma unroll
  for (int r = 0; r < 4; ++r) {
    float i1 = 1.0f / l1[r];
    float i2 = lam / l2[r];
    float vals[16];
    float ssq = 0.f;
#pragma unroll
    for (int eb = 0; eb < 16; ++eb) {
      float v = o1[eb][r] * i1 - o2[eb][r] * i2;
      vals[eb] = v;
      ssq += v * v;
    }
#pragma unroll
    for (int off = 1; off < 16; off <<= 1) ssq += __shfl_xor(ssq, off, 64);
    float rinv = rsqrtf(ssq * (1.0f / 256.0f) + RMS_EPS);
    const int q = q0 + w * 16 + lhi * 4 + r;
    const size_t ob = ((size_t)b * NSEQ + q) * E + (size_t)h * 256;
#pragma unroll
    for (int eb = 0; eb < 16; ++eb) {
      int e = eb * 16 + l15;
      Ob[ob + e] = (bf16)(vals[eb] * rinv * rms_scale[e] * osc);
    }
  }
}

// ---------------------------------------------------------------- launch
extern "C" void kernel_launch(void* const* d_in, const int* in_sizes, int n_in,
                              void* d_out, int out_size, void* d_ws, size_t ws_size,
                              hipStream_t stream) {
  const float* X   = (const float*)d_in[0];
  const float* Wq  = (const float*)d_in[1];
  const float* Wk  = (const float*)d_in[2];
  const float* Wv  = (const float*)d_in[3];
  const float* Wo  = (const float*)d_in[4];
  const float* lq1 = (const float*)d_in[5];
  const float* lk1 = (const float*)d_in[6];
  const float* lq2 = (const float*)d_in[7];
  const float* lk2 = (const float*)d_in[8];
  const float* rs  = (const float*)d_in[9];
  float* out = (float*)d_out;

  constexpr size_t B = 2, NSEQ = 2048, D = 1024, E = 2048;
  constexpr size_t M = B * NSEQ;  // 4096

  char* ws = (char*)d_ws;
  bf16* Xb  = (bf16*)ws;                 // M*D
  bf16* Wqb = Xb + M * D;                // E*D
  bf16* Wkb = Wqb + E * D;
  bf16* Wvb = Wkb + E * D;
  bf16* Wob = Wvb + E * D;               // D*E
  bf16* Qb  = Wob + D * E;               // M*E
  bf16* Kb  = Qb + M * E;
  bf16* Vb  = Kb + M * E;
  bf16* Ob  = Vb + M * E;                // M*E   (total ~88 MB)

  cast_f32_bf16<<<1024, 256, 0, stream>>>(X,  Xb,  (int)(M * D / 4));
  cast_f32_bf16<<<512,  256, 0, stream>>>(Wq, Wqb, (int)(E * D / 4));
  cast_f32_bf16<<<512,  256, 0, stream>>>(Wk, Wkb, (int)(E * D / 4));
  cast_f32_bf16<<<512,  256, 0, stream>>>(Wv, Wvb, (int)(E * D / 4));
  cast_f32_bf16<<<512,  256, 0, stream>>>(Wo, Wob, (int)(D * E / 4));

  gemm_bt<bf16><<<dim3(M / 128, E / 128), 256, 0, stream>>>(Xb, Wqb, Qb, (int)M, (int)E, (int)D);
  gemm_bt<bf16><<<dim3(M / 128, E / 128), 256, 0, stream>>>(Xb, Wkb, Kb, (int)M, (int)E, (int)D);
  gemm_bt<bf16><<<dim3(M / 128, E / 128), 256, 0, stream>>>(Xb, Wvb, Vb, (int)M, (int)E, (int)D);

  diff_attn<<<dim3(NSEQ / 64, 8, B), 256, 0, stream>>>(Qb, Kb, Vb, lq1, lk1, lq2, lk2, rs, Ob);

  gemm_bt<float><<<dim3(M / 128, D / 128), 256, 0, stream>>>(Ob, Wob, out, (int)M, (int)D, (int)E);
}

// Round 2
// 542.481 us; speedup vs baseline: 1.7523x; 1.7523x over previous
//
#include <hip/hip_runtime.h>
#include <hip/hip_bf16.h>

typedef __bf16 bf16;
typedef __attribute__((ext_vector_type(8))) __bf16 bf16x8;
typedef __attribute__((ext_vector_type(4))) float f32x4;

#define LAMBDA_INIT_F 0.3555090675909693f
#define RMS_EPS 1e-5f

// ---------------------------------------------------------------- cast f32 -> bf16
__global__ void cast_f32_bf16(const float* __restrict__ in, bf16* __restrict__ out, int n4) {
  int idx = blockIdx.x * blockDim.x + threadIdx.x;
  int stride = gridDim.x * blockDim.x;
  for (int i = idx; i < n4; i += stride) {
    float4 v = reinterpret_cast<const float4*>(in)[i];
    bf16 o[4];
    o[0] = (bf16)v.x; o[1] = (bf16)v.y; o[2] = (bf16)v.z; o[3] = (bf16)v.w;
    *reinterpret_cast<ushort4*>(&out[(size_t)i * 4]) = *reinterpret_cast<const ushort4*>(o);
  }
}

// ---------------------------------------------------------------- bt-GEMM
// C[m,n] = sum_k A[m,k] * B[n,k]   (A: MxK row-major, B: NxK row-major)
// MODE 0: bf16 out, row-major.  MODE 1: float out, row-major.
// MODE 2: bf16 out, written as Vt[b, h, e, n_seq]  (m=(b,nq), col=(h,e))
template <int MODE>
__global__ __launch_bounds__(256) void gemm_bt(
    const bf16* __restrict__ A, const bf16* __restrict__ B,
    void* __restrict__ Cv, int M, int N, int K) {
  constexpr int BM = 128, BN = 128, BK = 32, LDP = BK + 8;  // pad keeps 16B align (80B rows)
  __shared__ __align__(16) bf16 As[BM][LDP];
  __shared__ __align__(16) bf16 Bs[BN][LDP];
  const int tid = threadIdx.x;
  const int lane = tid & 63;
  const int w = tid >> 6;
  const int wr = (w >> 1) * 64, wc = (w & 1) * 64;
  const int l15 = lane & 15, lhi = lane >> 4;
  const int bm = blockIdx.x * BM, bn = blockIdx.y * BN;
  f32x4 acc[4][4] = {};

  for (int k0 = 0; k0 < K; k0 += BK) {
    __syncthreads();
#pragma unroll
    for (int i = 0; i < 2; ++i) {
      int f = i * 256 + tid;   // 0..511 ; 4 threads per 32-elem row
      int row = f >> 2;
      int c8 = (f & 3) * 8;
      *reinterpret_cast<uint4*>(&As[row][c8]) =
          *reinterpret_cast<const uint4*>(&A[(size_t)(bm + row) * K + k0 + c8]);
      *reinterpret_cast<uint4*>(&Bs[row][c8]) =
          *reinterpret_cast<const uint4*>(&B[(size_t)(bn + row) * K + k0 + c8]);
    }
    __syncthreads();
    bf16x8 af[4], bfr[4];
#pragma unroll
    for (int mf = 0; mf < 4; ++mf)
      af[mf] = *reinterpret_cast<const bf16x8*>(&As[wr + mf * 16 + l15][lhi * 8]);
#pragma unroll
    for (int nf = 0; nf < 4; ++nf)
      bfr[nf] = *reinterpret_cast<const bf16x8*>(&Bs[wc + nf * 16 + l15][lhi * 8]);
#pragma unroll
    for (int mf = 0; mf < 4; ++mf)
#pragma unroll
      for (int nf = 0; nf < 4; ++nf)
        acc[mf][nf] = __builtin_amdgcn_mfma_f32_16x16x32_bf16(af[mf], bfr[nf], acc[mf][nf], 0, 0, 0);
  }
  // epilogue: C/D layout col=lane&15, row=(lane>>4)*4+r
#pragma unroll
  for (int mf = 0; mf < 4; ++mf)
#pragma unroll
    for (int nf = 0; nf < 4; ++nf)
#pragma unroll
      for (int r = 0; r < 4; ++r) {
        int m = bm + wr + mf * 16 + lhi * 4 + r;
        int n = bn + wc + nf * 16 + l15;
        if constexpr (MODE == 0) {
          ((bf16*)Cv)[(size_t)m * N + n] = (bf16)acc[mf][nf][r];
        } else if constexpr (MODE == 1) {
          ((float*)Cv)[(size_t)m * N + n] = acc[mf][nf][r];
        } else {
          // Vt[b, h, e, n_seq]:  m = b*2048 + nq ; n = h*256 + e
          int bb = m >> 11, nq = m & 2047;
          int hh = n >> 8, e = n & 255;
          ((bf16*)Cv)[((((size_t)bb * 8 + hh) * 256 + e) << 11) + nq] = (bf16)acc[mf][nf][r];
        }
      }
}

// ---------------------------------------------------------------- differential flash attention
// grid: (N/64, H, B), block 256 (4 waves x 16 q-rows)
// Vtg is V pre-transposed: [b, h, e, n_seq]
__global__ __launch_bounds__(256) void diff_attn(
    const bf16* __restrict__ Q, const bf16* __restrict__ Kb, const bf16* __restrict__ Vtg,
    const float* __restrict__ lq1, const float* __restrict__ lk1,
    const float* __restrict__ lq2, const float* __restrict__ lk2,
    const float* __restrict__ rms_scale, bf16* __restrict__ Ob) {
  constexpr int NSEQ = 2048, E = 2048, KT = 32;
  __shared__ __align__(16) bf16 Ks[KT][264];        // key-major, 256 dims + pad8 (row 528B)
  __shared__ __align__(16) bf16 Vs[256][40];        // e-major, staged from Vtg (row 80B)
  __shared__ __align__(16) bf16 Ps[4][16][40];      // per-wave P staging
  const int tid = threadIdx.x, lane = tid & 63, w = tid >> 6;
  const int l15 = lane & 15, lhi = lane >> 4;
  const int b = blockIdx.z, h = blockIdx.y;
  const int q0 = blockIdx.x * 64;

  // lambda scalar for this head
  float sl1 = 0.f, sl2 = 0.f;
  for (int i = 0; i < 128; ++i) {
    sl1 += lq1[h * 128 + i] * lk1[h * 128 + i];
    sl2 += lq2[h * 128 + i] * lk2[h * 128 + i];
  }
  const float lam = __expf(sl1) - __expf(sl2) + LAMBDA_INIT_F;

  // Q fragments (A-frag: row = lane&15, k = lhi*8+j)
  const int qrow = q0 + w * 16 + l15;
  const size_t qbase = ((size_t)b * NSEQ + qrow) * E + (size_t)h * 256;
  bf16x8 q1f[4], q2f[4];
#pragma unroll
  for (int df = 0; df < 4; ++df) {
    q1f[df] = *reinterpret_cast<const bf16x8*>(&Q[qbase + df * 32 + lhi * 8]);
    q2f[df] = *reinterpret_cast<const bf16x8*>(&Q[qbase + 128 + df * 32 + lhi * 8]);
  }

  f32x4 o1[16] = {}, o2[16] = {};
  float m1[4], l1[4], m2[4], l2[4];
#pragma unroll
  for (int r = 0; r < 4; ++r) { m1[r] = m2[r] = -1e30f; l1[r] = l2[r] = 0.f; }

  // QK^T + online softmax for one stream; returns the P A-fragment (bf16) and
  // rescales the accumulator. Per-wave only: no block barrier inside.
  auto softmax_part = [&](int d0, const bf16x8* qf, float* mm, float* ll, f32x4* oo) -> bf16x8 {
    f32x4 s[2] = {};
#pragma unroll
    for (int cb = 0; cb < 2; ++cb)
#pragma unroll
      for (int df = 0; df < 4; ++df) {
        bf16x8 kf = *reinterpret_cast<const bf16x8*>(&Ks[cb * 16 + l15][d0 + df * 32 + lhi * 8]);
        s[cb] = __builtin_amdgcn_mfma_f32_16x16x32_bf16(qf[df], kf, s[cb], 0, 0, 0);
      }
    constexpr float sc = 0.08838834764831845f;  // 1/sqrt(128)
    float alpha[4];
#pragma unroll
    for (int r = 0; r < 4; ++r) {
      float v0 = s[0][r] * sc, v1 = s[1][r] * sc;
      float mx = fmaxf(v0, v1);
#pragma unroll
      for (int off = 1; off < 16; off <<= 1) mx = fmaxf(mx, __shfl_xor(mx, off, 64));
      float mnew = fmaxf(mm[r], mx);
      float al = __expf(mm[r] - mnew);
      float p0 = __expf(v0 - mnew);
      float p1 = __expf(v1 - mnew);
      float rsum = p0 + p1;
#pragma unroll
      for (int off = 1; off < 16; off <<= 1) rsum += __shfl_xor(rsum, off, 64);
      ll[r] = ll[r] * al + rsum;
      mm[r] = mnew;
      alpha[r] = al;
      // P -> per-wave LDS (S layout: col=lane&15 is key, row=lhi*4+r is q)
      Ps[w][lhi * 4 + r][l15] = (bf16)p0;
      Ps[w][lhi * 4 + r][16 + l15] = (bf16)p1;
    }
#pragma unroll
    for (int eb = 0; eb < 16; ++eb) {
      oo[eb][0] *= alpha[0]; oo[eb][1] *= alpha[1];
      oo[eb][2] *= alpha[2]; oo[eb][3] *= alpha[3];
    }
    // per-wave visibility of the Ps writes, then read back as A-frag
    asm volatile("s_waitcnt lgkmcnt(0)" ::: "memory");
    __builtin_amdgcn_sched_barrier(0);
    return *reinterpret_cast<const bf16x8*>(&Ps[w][l15][lhi * 8]);
  };

  for (int kt0 = 0; kt0 < NSEQ; kt0 += KT) {
    __syncthreads();
    // stage K tile: 32 keys x 256 dims (1024 uint4, vectorized)
#pragma unroll
    for (int i = 0; i < 4; ++i) {
      int f = i * 256 + tid;
      int key = f >> 5;
      int e8 = (f & 31) * 8;
      *reinterpret_cast<uint4*>(&Ks[key][e8]) =
          *reinterpret_cast<const uint4*>(&Kb[((size_t)b * NSEQ + kt0 + key) * E + (size_t)h * 256 + e8]);
    }
    // stage V tile from pre-transposed Vtg: 256 e-rows x 32 keys (1024 uint4)
#pragma unroll
    for (int i = 0; i < 4; ++i) {
      int f = i * 256 + tid;
      int e = f >> 2;
      int k8 = (f & 3) * 8;
      *reinterpret_cast<uint4*>(&Vs[e][k8]) =
          *reinterpret_cast<const uint4*>(&Vtg[((((size_t)b * 8 + h) * 256 + e) << 11) + kt0 + k8]);
    }
    __syncthreads();

    bf16x8 pa1 = softmax_part(0,   q1f, m1, l1, o1);
    bf16x8 pa2 = softmax_part(128, q2f, m2, l2, o2);

    // PV for both streams, sharing each V fragment read
#pragma unroll
    for (int eb = 0; eb < 16; ++eb) {
      bf16x8 vf = *reinterpret_cast<const bf16x8*>(&Vs[eb * 16 + l15][lhi * 8]);
      o1[eb] = __builtin_amdgcn_mfma_f32_16x16x32_bf16(pa1, vf, o1[eb], 0, 0, 0);
      o2[eb] = __builtin_amdgcn_mfma_f32_16x16x32_bf16(pa2, vf, o2[eb], 0, 0, 0);
    }
  }

  // epilogue: combine streams, RMS norm over 256 dims, scale, store bf16
  const float osc = 1.0f - LAMBDA_INIT_F;
#pragma unroll
  for (int r = 0; r < 4; ++r) {
    float i1 = 1.0f / l1[r];
    float i2 = lam / l2[r];
    float vals[16];
    float ssq = 0.f;
#pragma unroll
    for (int eb = 0; eb < 16; ++eb) {
      float v = o1[eb][r] * i1 - o2[eb][r] * i2;
      vals[eb] = v;
      ssq += v * v;
    }
#pragma unroll
    for (int off = 1; off < 16; off <<= 1) ssq += __shfl_xor(ssq, off, 64);
    float rinv = rsqrtf(ssq * (1.0f / 256.0f) + RMS_EPS);
    const int q = q0 + w * 16 + lhi * 4 + r;
    const size_t ob = ((size_t)b * NSEQ + q) * E + (size_t)h * 256;
#pragma unroll
    for (int eb = 0; eb < 16; ++eb) {
      int e = eb * 16 + l15;
      Ob[ob + e] = (bf16)(vals[eb] * rinv * rms_scale[e] * osc);
    }
  }
}

// ---------------------------------------------------------------- launch
extern "C" void kernel_launch(void* const* d_in, const int* in_sizes, int n_in,
                              void* d_out, int out_size, void* d_ws, size_t ws_size,
                              hipStream_t stream) {
  const float* X   = (const float*)d_in[0];
  const float* Wq  = (const float*)d_in[1];
  const float* Wk  = (const float*)d_in[2];
  const float* Wv  = (const float*)d_in[3];
  const float* Wo  = (const float*)d_in[4];
  const float* lq1 = (const float*)d_in[5];
  const float* lk1 = (const float*)d_in[6];
  const float* lq2 = (const float*)d_in[7];
  const float* lk2 = (const float*)d_in[8];
  const float* rs  = (const float*)d_in[9];
  float* out = (float*)d_out;

  constexpr size_t B = 2, NSEQ = 2048, D = 1024, E = 2048;
  constexpr size_t M = B * NSEQ;  // 4096

  char* ws = (char*)d_ws;
  bf16* Xb  = (bf16*)ws;                 // M*D
  bf16* Wqb = Xb + M * D;                // E*D
  bf16* Wkb = Wqb + E * D;
  bf16* Wvb = Wkb + E * D;
  bf16* Wob = Wvb + E * D;               // D*E
  bf16* Qb  = Wob + D * E;               // M*E
  bf16* Kb  = Qb + M * E;
  bf16* Vtb = Kb + M * E;                // M*E, layout [b,h,e,n]
  bf16* Ob  = Vtb + M * E;               // M*E

  cast_f32_bf16<<<1024, 256, 0, stream>>>(X,  Xb,  (int)(M * D / 4));
  cast_f32_bf16<<<512,  256, 0, stream>>>(Wq, Wqb, (int)(E * D / 4));
  cast_f32_bf16<<<512,  256, 0, stream>>>(Wk, Wkb, (int)(E * D / 4));
  cast_f32_bf16<<<512,  256, 0, stream>>>(Wv, Wvb, (int)(E * D / 4));
  cast_f32_bf16<<<512,  256, 0, stream>>>(Wo, Wob, (int)(D * E / 4));

  gemm_bt<0><<<dim3(M / 128, E / 128), 256, 0, stream>>>(Xb, Wqb, Qb, (int)M, (int)E, (int)D);
  gemm_bt<0><<<dim3(M / 128, E / 128), 256, 0, stream>>>(Xb, Wkb, Kb, (int)M, (int)E, (int)D);
  gemm_bt<2><<<dim3(M / 128, E / 128), 256, 0, stream>>>(Xb, Wvb, Vtb, (int)M, (int)E, (int)D);

  diff_attn<<<dim3(NSEQ / 64, 8, B), 256, 0, stream>>>(Qb, Kb, Vtb, lq1, lk1, lq2, lk2, rs, Ob);

  gemm_bt<1><<<dim3(M / 128, D / 128), 256, 0, stream>>>(Ob, Wob, out, (int)M, (int)D, (int)E);
}

// Round 3
// 340.164 us; speedup vs baseline: 2.7944x; 1.5948x over previous
//
#include <hip/hip_runtime.h>
#include <hip/hip_bf16.h>

typedef __bf16 bf16;
typedef __attribute__((ext_vector_type(8))) __bf16 bf16x8;
typedef __attribute__((ext_vector_type(4))) float f32x4;

#define LAMBDA_INIT_F 0.3555090675909693f
#define RMS_EPS 1e-5f

// ---------------------------------------------------------------- cast f32 -> bf16
__global__ void cast_f32_bf16(const float* __restrict__ in, bf16* __restrict__ out, int n4) {
  int idx = blockIdx.x * blockDim.x + threadIdx.x;
  int stride = gridDim.x * blockDim.x;
  for (int i = idx; i < n4; i += stride) {
    float4 v = reinterpret_cast<const float4*>(in)[i];
    bf16 o[4];
    o[0] = (bf16)v.x; o[1] = (bf16)v.y; o[2] = (bf16)v.z; o[3] = (bf16)v.w;
    *reinterpret_cast<ushort4*>(&out[(size_t)i * 4]) = *reinterpret_cast<const ushort4*>(o);
  }
}

// ---------------------------------------------------------------- bt-GEMM
// C[m,n] = sum_k A[m,k] * B[n,k]   (A: MxK row-major, B: NxK row-major)
// MODE 0: bf16 out, row-major.  MODE 1: float out, row-major.
// MODE 2: bf16 out, written as Vt[b, h, e, n_seq]  (m=(b,nq), col=(h,e))
template <int MODE>
__global__ __launch_bounds__(256) void gemm_bt(
    const bf16* __restrict__ A, const bf16* __restrict__ B,
    void* __restrict__ Cv, int M, int N, int K) {
  constexpr int BM = 128, BN = 128, BK = 32, LDP = BK + 8;
  __shared__ __align__(16) bf16 As[BM][LDP];
  __shared__ __align__(16) bf16 Bs[BN][LDP];
  const int tid = threadIdx.x;
  const int lane = tid & 63;
  const int w = tid >> 6;
  const int wr = (w >> 1) * 64, wc = (w & 1) * 64;
  const int l15 = lane & 15, lhi = lane >> 4;
  const int bm = blockIdx.x * BM, bn = blockIdx.y * BN;
  f32x4 acc[4][4] = {};

  for (int k0 = 0; k0 < K; k0 += BK) {
    __syncthreads();
#pragma unroll
    for (int i = 0; i < 2; ++i) {
      int f = i * 256 + tid;
      int row = f >> 2;
      int c8 = (f & 3) * 8;
      *reinterpret_cast<uint4*>(&As[row][c8]) =
          *reinterpret_cast<const uint4*>(&A[(size_t)(bm + row) * K + k0 + c8]);
      *reinterpret_cast<uint4*>(&Bs[row][c8]) =
          *reinterpret_cast<const uint4*>(&B[(size_t)(bn + row) * K + k0 + c8]);
    }
    __syncthreads();
    bf16x8 af[4], bfr[4];
#pragma unroll
    for (int mf = 0; mf < 4; ++mf)
      af[mf] = *reinterpret_cast<const bf16x8*>(&As[wr + mf * 16 + l15][lhi * 8]);
#pragma unroll
    for (int nf = 0; nf < 4; ++nf)
      bfr[nf] = *reinterpret_cast<const bf16x8*>(&Bs[wc + nf * 16 + l15][lhi * 8]);
#pragma unroll
    for (int mf = 0; mf < 4; ++mf)
#pragma unroll
      for (int nf = 0; nf < 4; ++nf)
        acc[mf][nf] = __builtin_amdgcn_mfma_f32_16x16x32_bf16(af[mf], bfr[nf], acc[mf][nf], 0, 0, 0);
  }
#pragma unroll
  for (int mf = 0; mf < 4; ++mf)
#pragma unroll
    for (int nf = 0; nf < 4; ++nf)
#pragma unroll
      for (int r = 0; r < 4; ++r) {
        int m = bm + wr + mf * 16 + lhi * 4 + r;
        int n = bn + wc + nf * 16 + l15;
        if constexpr (MODE == 0) {
          ((bf16*)Cv)[(size_t)m * N + n] = (bf16)acc[mf][nf][r];
        } else if constexpr (MODE == 1) {
          ((float*)Cv)[(size_t)m * N + n] = acc[mf][nf][r];
        } else {
          int bb = m >> 11, nq = m & 2047;
          int hh = n >> 8, e = n & 255;
          ((bf16*)Cv)[((((size_t)bb * 8 + hh) * 256 + e) << 11) + nq] = (bf16)acc[mf][nf][r];
        }
      }
}

// ---------------------------------------------------------------- differential flash attention
// grid: (N/64, H, B), block 256 (4 waves x 16 q-rows)
// Vtg is V pre-transposed: [b, h, e, n_seq]
// Swapped QK^T: S = mfma(K_frag, Q_frag) -> lane holds 8 P-values of one q-row
// (keys {4*lhi+r} U {16+4*lhi+r}). V is staged key-PERMUTED in LDS
// (slot 8g+4h+c <- key 16h+4g+c) so those 8 values in natural order form the
// PV A-fragment directly: softmax is fully in-register, no P LDS round-trip.
__global__ __launch_bounds__(256, 2) void diff_attn(
    const bf16* __restrict__ Q, const bf16* __restrict__ Kb, const bf16* __restrict__ Vtg,
    const float* __restrict__ lq1, const float* __restrict__ lk1,
    const float* __restrict__ lq2, const float* __restrict__ lk2,
    const float* __restrict__ rms_scale, bf16* __restrict__ Ob) {
  constexpr int NSEQ = 2048, E = 2048, KT = 32, NT = NSEQ / KT;
  constexpr float SC = 0.08838834764831845f;   // 1/sqrt(128)
  constexpr float DEFER_RAW = 90.50966799f;    // 8 / SC
  __shared__ __align__(16) bf16 Ks[2][KT][264];
  __shared__ __align__(16) bf16 Vs[2][256][40];
  const int tid = threadIdx.x, lane = tid & 63, w = tid >> 6;
  const int l15 = lane & 15, lhi = (lane >> 4) & 3;
  const int b = blockIdx.z, h = blockIdx.y;
  const int q0 = blockIdx.x * 64;

  // lambda scalar for this head
  float sl1 = 0.f, sl2 = 0.f;
  for (int i = 0; i < 128; ++i) {
    sl1 += lq1[h * 128 + i] * lk1[h * 128 + i];
    sl2 += lq2[h * 128 + i] * lk2[h * 128 + i];
  }
  const float lam = __expf(sl1) - __expf(sl2) + LAMBDA_INIT_F;

  // Q fragments (B-operand: col = lane&15 = q, k = lhi*8+j)
  const int qrow = q0 + w * 16 + l15;
  const size_t qbase = ((size_t)b * NSEQ + qrow) * E + (size_t)h * 256;
  bf16x8 q1f[4], q2f[4];
#pragma unroll
  for (int df = 0; df < 4; ++df) {
    q1f[df] = *reinterpret_cast<const bf16x8*>(&Q[qbase + df * 32 + lhi * 8]);
    q2f[df] = *reinterpret_cast<const bf16x8*>(&Q[qbase + 128 + df * 32 + lhi * 8]);
  }

  const bf16* Kbase = Kb + ((size_t)b * NSEQ) * E + (size_t)h * 256;
  const bf16* Vbase = Vtg + (((size_t)b * 8 + h) * 256) * (size_t)NSEQ;

  f32x4 o1[16] = {}, o2[16] = {};
  float mm1 = -3e38f, mm2 = -3e38f, ll1 = 0.f, ll2 = 0.f;

  uint4 kst[4], vst[4];

  auto issue = [&](int t) {
    const int kt0 = t * KT;
#pragma unroll
    for (int i = 0; i < 4; ++i) {
      int f = i * 256 + tid;
      int key = f >> 5, e8 = (f & 31) * 8;
      kst[i] = *reinterpret_cast<const uint4*>(&Kbase[(size_t)(kt0 + key) * E + e8]);
    }
#pragma unroll
    for (int i = 0; i < 4; ++i) {
      int f = i * 256 + tid;
      int e = f >> 2, k8 = (f & 3) * 8;
      vst[i] = *reinterpret_cast<const uint4*>(&Vbase[(size_t)e * NSEQ + kt0 + k8]);
    }
  };
  auto lds_write = [&](int bsel) {
#pragma unroll
    for (int i = 0; i < 4; ++i) {
      int f = i * 256 + tid;
      int key = f >> 5, e8 = (f & 31) * 8;
      *reinterpret_cast<uint4*>(&Ks[bsel][key][e8]) = kst[i];
    }
#pragma unroll
    for (int i = 0; i < 4; ++i) {
      int f = i * 256 + tid;
      int e = f >> 2, k8 = (f & 3) * 8;
      int s0 = ((k8 & 8) << 1) | ((k8 >> 4) << 2);  // key 16h+4g -> slot 8g+4h
      uint2 lo, hi;
      lo.x = vst[i].x; lo.y = vst[i].y;
      hi.x = vst[i].z; hi.y = vst[i].w;
      *reinterpret_cast<uint2*>(&Vs[bsel][e][s0]) = lo;
      *reinterpret_cast<uint2*>(&Vs[bsel][e][s0 + 8]) = hi;
    }
  };

  // softmax over one stream's raw scores; returns PV A-frag
  auto softmax = [&](const f32x4* s, float& mmr, float& llr, f32x4* oo) -> bf16x8 {
    float p[8];
#pragma unroll
    for (int r = 0; r < 4; ++r) { p[r] = s[0][r]; p[4 + r] = s[1][r]; }
    float mx = fmaxf(fmaxf(fmaxf(p[0], p[1]), fmaxf(p[2], p[3])),
                     fmaxf(fmaxf(p[4], p[5]), fmaxf(p[6], p[7])));
    mx = fmaxf(mx, __shfl_xor(mx, 16, 64));
    mx = fmaxf(mx, __shfl_xor(mx, 32, 64));
    if (!__all(mx <= mmr + DEFER_RAW)) {
      float mnew = fmaxf(mmr, mx);
      float al = __expf((mmr - mnew) * SC);
      mmr = mnew;
      llr *= al;
      float af[4];
#pragma unroll
      for (int r = 0; r < 4; ++r) af[r] = __shfl(al, 4 * lhi + r, 64);
#pragma unroll
      for (int eb = 0; eb < 16; ++eb) {
        oo[eb][0] *= af[0]; oo[eb][1] *= af[1];
        oo[eb][2] *= af[2]; oo[eb][3] *= af[3];
      }
    }
    const float msc = mmr * SC;
    float rsum = 0.f;
    bf16 pb[8];
#pragma unroll
    for (int j = 0; j < 8; ++j) {
      float e = __expf(__fmaf_rn(p[j], SC, -msc));
      rsum += e;
      pb[j] = (bf16)e;
    }
    rsum += __shfl_xor(rsum, 16, 64);
    rsum += __shfl_xor(rsum, 32, 64);
    llr += rsum;
    return *reinterpret_cast<const bf16x8*>(pb);
  };

  // prologue: stage tile 0
  issue(0);
  lds_write(0);

  for (int t = 0; t < NT; ++t) {
    const int bsel = t & 1;
    if (t + 1 < NT) issue(t + 1);
    __builtin_amdgcn_sched_barrier(0);
    __syncthreads();

    // QK^T swapped: s[cb] = S_raw[key = cb*16 + 4*lhi + r][q = l15]
    f32x4 sA[2] = {}, sB[2] = {};
#pragma unroll
    for (int df = 0; df < 4; ++df) {
      bf16x8 kf0 = *reinterpret_cast<const bf16x8*>(&Ks[bsel][l15][df * 32 + lhi * 8]);
      bf16x8 kf1 = *reinterpret_cast<const bf16x8*>(&Ks[bsel][16 + l15][df * 32 + lhi * 8]);
      sA[0] = __builtin_amdgcn_mfma_f32_16x16x32_bf16(kf0, q1f[df], sA[0], 0, 0, 0);
      sA[1] = __builtin_amdgcn_mfma_f32_16x16x32_bf16(kf1, q1f[df], sA[1], 0, 0, 0);
      bf16x8 kf2 = *reinterpret_cast<const bf16x8*>(&Ks[bsel][l15][128 + df * 32 + lhi * 8]);
      bf16x8 kf3 = *reinterpret_cast<const bf16x8*>(&Ks[bsel][16 + l15][128 + df * 32 + lhi * 8]);
      sB[0] = __builtin_amdgcn_mfma_f32_16x16x32_bf16(kf2, q2f[df], sB[0], 0, 0, 0);
      sB[1] = __builtin_amdgcn_mfma_f32_16x16x32_bf16(kf3, q2f[df], sB[1], 0, 0, 0);
    }

    bf16x8 pa1 = softmax(sA, mm1, ll1, o1);
    bf16x8 pa2 = softmax(sB, mm2, ll2, o2);

    __builtin_amdgcn_s_setprio(1);
#pragma unroll
    for (int eb = 0; eb < 16; ++eb) {
      bf16x8 vf = *reinterpret_cast<const bf16x8*>(&Vs[bsel][eb * 16 + l15][lhi * 8]);
      o1[eb] = __builtin_amdgcn_mfma_f32_16x16x32_bf16(pa1, vf, o1[eb], 0, 0, 0);
      o2[eb] = __builtin_amdgcn_mfma_f32_16x16x32_bf16(pa2, vf, o2[eb], 0, 0, 0);
    }
    __builtin_amdgcn_s_setprio(0);

    if (t + 1 < NT) lds_write(bsel ^ 1);
  }

  // epilogue: combine streams, RMS norm over 256 dims, scale, store bf16
  const float osc = 1.0f - LAMBDA_INIT_F;
  float L1[4], L2[4];
#pragma unroll
  for (int r = 0; r < 4; ++r) {
    L1[r] = __shfl(ll1, 4 * lhi + r, 64);
    L2[r] = __shfl(ll2, 4 * lhi + r, 64);
  }
#pragma unroll
  for (int r = 0; r < 4; ++r) {
    float i1 = 1.0f / L1[r];
    float i2 = lam / L2[r];
    float vals[16];
    float ssq = 0.f;
#pragma unroll
    for (int eb = 0; eb < 16; ++eb) {
      float v = o1[eb][r] * i1 - o2[eb][r] * i2;
      vals[eb] = v;
      ssq += v * v;
    }
#pragma unroll
    for (int off = 1; off < 16; off <<= 1) ssq += __shfl_xor(ssq, off, 64);
    float rinv = rsqrtf(ssq * (1.0f / 256.0f) + RMS_EPS);
    const int q = q0 + w * 16 + lhi * 4 + r;
    const size_t ob = ((size_t)b * NSEQ + q) * E + (size_t)h * 256;
#pragma unroll
    for (int eb = 0; eb < 16; ++eb) {
      int e = eb * 16 + l15;
      Ob[ob + e] = (bf16)(vals[eb] * rinv * rms_scale[e] * osc);
    }
  }
}

// ---------------------------------------------------------------- launch
extern "C" void kernel_launch(void* const* d_in, const int* in_sizes, int n_in,
                              void* d_out, int out_size, void* d_ws, size_t ws_size,
                              hipStream_t stream) {
  const float* X   = (const float*)d_in[0];
  const float* Wq  = (const float*)d_in[1];
  const float* Wk  = (const float*)d_in[2];
  const float* Wv  = (const float*)d_in[3];
  const float* Wo  = (const float*)d_in[4];
  const float* lq1 = (const float*)d_in[5];
  const float* lk1 = (const float*)d_in[6];
  const float* lq2 = (const float*)d_in[7];
  const float* lk2 = (const float*)d_in[8];
  const float* rs  = (const float*)d_in[9];
  float* out = (float*)d_out;

  constexpr size_t B = 2, NSEQ = 2048, D = 1024, E = 2048;
  constexpr size_t M = B * NSEQ;  // 4096

  char* ws = (char*)d_ws;
  bf16* Xb  = (bf16*)ws;                 // M*D
  bf16* Wqb = Xb + M * D;                // E*D
  bf16* Wkb = Wqb + E * D;
  bf16* Wvb = Wkb + E * D;
  bf16* Wob = Wvb + E * D;               // D*E
  bf16* Qb  = Wob + D * E;               // M*E
  bf16* Kb  = Qb + M * E;
  bf16* Vtb = Kb + M * E;                // M*E, layout [b,h,e,n]
  bf16* Ob  = Vtb + M * E;               // M*E

  cast_f32_bf16<<<1024, 256, 0, stream>>>(X,  Xb,  (int)(M * D / 4));
  cast_f32_bf16<<<512,  256, 0, stream>>>(Wq, Wqb, (int)(E * D / 4));
  cast_f32_bf16<<<512,  256, 0, stream>>>(Wk, Wkb, (int)(E * D / 4));
  cast_f32_bf16<<<512,  256, 0, stream>>>(Wv, Wvb, (int)(E * D / 4));
  cast_f32_bf16<<<512,  256, 0, stream>>>(Wo, Wob, (int)(D * E / 4));

  gemm_bt<0><<<dim3(M / 128, E / 128), 256, 0, stream>>>(Xb, Wqb, Qb, (int)M, (int)E, (int)D);
  gemm_bt<0><<<dim3(M / 128, E / 128), 256, 0, stream>>>(Xb, Wkb, Kb, (int)M, (int)E, (int)D);
  gemm_bt<2><<<dim3(M / 128, E / 128), 256, 0, stream>>>(Xb, Wvb, Vtb, (int)M, (int)E, (int)D);

  diff_attn<<<dim3(NSEQ / 64, 8, B), 256, 0, stream>>>(Qb, Kb, Vtb, lq1, lk1, lq2, lk2, rs, Ob);

  gemm_bt<1><<<dim3(M / 128, D / 128), 256, 0, stream>>>(Ob, Wob, out, (int)M, (int)D, (int)E);
}